// Round 1
// baseline (3576.582 us; speedup 1.0000x reference)
//
#include <hip/hip_runtime.h>
#include <hip/hip_bf16.h>
#include <math.h>

#define BB 16
#define LL 256
#define DM 256
#define DI 512
#define DS 16
#define DTR 16
#define NTOK (BB*LL)
#define LN_EPS 1e-5f

__device__ __forceinline__ float siluf(float x) { return x / (1.f + expf(-x)); }

// ---- block reduce (sum, sumsq) over 256 threads ----
__device__ __forceinline__ void block_reduce2(float& s, float& s2, float* red) {
    #pragma unroll
    for (int off = 32; off; off >>= 1) {
        s  += __shfl_down(s,  off);
        s2 += __shfl_down(s2, off);
    }
    int wid = threadIdx.x >> 6;
    if ((threadIdx.x & 63) == 0) { red[wid*2] = s; red[wid*2+1] = s2; }
    __syncthreads();
    s  = red[0] + red[2] + red[4] + red[6];
    s2 = red[1] + red[3] + red[5] + red[7];
}

// ---- fused embedding gather + holographic bind (direct circular conv) + layernorm ----
__global__ __launch_bounds__(256)
void embed_holo_ln(const int* __restrict__ seq, const int* __restrict__ attr,
                   const float* __restrict__ item_emb, const float* __restrict__ attr_emb,
                   const float* __restrict__ alpha_p, const float* __restrict__ ln_s,
                   const float* __restrict__ ln_b, float* __restrict__ x) {
    int t = blockIdx.x;          // token
    int k = threadIdx.x;         // 0..255
    __shared__ float ei[DM], ea[DM];
    __shared__ float red[8];
    int si = seq[t], ai = attr[t];
    ei[k] = (si == 0) ? 0.f : item_emb[(size_t)si * DM + k];   // padding_idx=0
    ea[k] = (ai == 0) ? 0.f : attr_emb[(size_t)ai * DM + k];
    __syncthreads();
    // circ conv: (1/sqrt(256)) * sum_j ei[j]*ea[(k-j) mod 256]  == ortho-rfft holo_bind
    float conv = 0.f;
    #pragma unroll 8
    for (int j = 0; j < DM; ++j)
        conv = fmaf(ei[j], ea[(k - j) & (DM - 1)], conv);
    float v = fmaf(alpha_p[0] * 0.0625f, conv, ei[k]);
    // layernorm
    float s = v, s2 = v * v;
    block_reduce2(s, s2, red);
    float m  = s * (1.f / DM);
    float var = s2 * (1.f / DM) - m * m;
    x[(size_t)t * DM + k] = (v - m) * rsqrtf(var + LN_EPS) * ln_s[k] + ln_b[k];
}

// ---- per-layer layernorm ----
__global__ __launch_bounds__(256)
void ln_layer(const float* __restrict__ in, const float* __restrict__ sc,
              const float* __restrict__ bi, float* __restrict__ out) {
    int t = blockIdx.x, k = threadIdx.x;
    __shared__ float red[8];
    float v = in[(size_t)t * DM + k];
    float s = v, s2 = v * v;
    block_reduce2(s, s2, red);
    float m  = s * (1.f / DM);
    float var = s2 * (1.f / DM) - m * m;
    out[(size_t)t * DM + k] = (v - m) * rsqrtf(var + LN_EPS) * sc[k] + bi[k];
}

// ---- generic fp32 GEMM: C[M,N] (+)= A[M,K] @ B[K,N], row-major ----
// BM=BN=128, BK=16, 256 threads, 8x8 per thread. M%128==0, K%16==0 assumed; N guarded.
template<bool ACC>
__global__ __launch_bounds__(256)
void gemm_f32(const float* __restrict__ A, const float* __restrict__ B,
              float* __restrict__ C, int M, int N, int K) {
    __shared__ float As[16][128];
    __shared__ float Bs[16][128];
    int tid = threadIdx.x;
    int tx = tid & 15, ty = tid >> 4;
    int row0 = blockIdx.y * 128;
    int col0 = blockIdx.x * 128;
    float acc[8][8] = {};
    for (int k0 = 0; k0 < K; k0 += 16) {
        {   // A tile: 128x16, thread -> r=tid>>1, kb=(tid&1)*8
            int r = tid >> 1, kb = (tid & 1) * 8;
            const float* ap = A + (size_t)(row0 + r) * K + k0 + kb;
            #pragma unroll
            for (int i = 0; i < 8; ++i) As[kb + i][r] = ap[i];
        }
        {   // B tile: 16x128, thread -> kr=tid>>4, cb=(tid&15)*8
            int kr = tid >> 4, cb = (tid & 15) * 8;
            const float* bp = B + (size_t)(k0 + kr) * N + col0 + cb;
            #pragma unroll
            for (int i = 0; i < 8; ++i)
                Bs[kr][cb + i] = (col0 + cb + i < N) ? bp[i] : 0.f;
        }
        __syncthreads();
        #pragma unroll
        for (int kk = 0; kk < 16; ++kk) {
            float a[8], b[8];
            #pragma unroll
            for (int i = 0; i < 8; ++i) a[i] = As[kk][ty * 8 + i];
            #pragma unroll
            for (int j = 0; j < 8; ++j) b[j] = Bs[kk][tx * 8 + j];
            #pragma unroll
            for (int i = 0; i < 8; ++i)
                #pragma unroll
                for (int j = 0; j < 8; ++j)
                    acc[i][j] = fmaf(a[i], b[j], acc[i][j]);
        }
        __syncthreads();
    }
    #pragma unroll
    for (int i = 0; i < 8; ++i) {
        int r = row0 + ty * 8 + i;
        #pragma unroll
        for (int j = 0; j < 8; ++j) {
            int c = col0 + tx * 8 + j;
            if (c < N) {
                float* p = C + (size_t)r * N + c;
                if (ACC) *p += acc[i][j]; else *p = acc[i][j];
            }
        }
    }
}

// ---- causal depthwise conv (width 4, left pad 3) + bias + silu ----
// xz: [NTOK,1024] (xi = cols 0..511), out xc: [NTOK,512]
__global__ __launch_bounds__(256)
void conv_silu(const float* __restrict__ xz, const float* __restrict__ w,
               const float* __restrict__ cb, float* __restrict__ xc) {
    int t = blockIdx.x;
    int d = (blockIdx.y << 8) + threadIdx.x;
    int l = t & (LL - 1);
    float acc = cb[d];
    #pragma unroll
    for (int tt = 0; tt < 4; ++tt) {
        int ls = l - 3 + tt;
        if (ls >= 0) acc = fmaf(xz[(size_t)(t - 3 + tt) * (2 * DI) + d], w[d * 4 + tt], acc);
    }
    xc[(size_t)t * DI + d] = siluf(acc);
}

// ---- dt projection: softplus(dt[16] @ dt_w[16,512] + dt_b) ----
__global__ __launch_bounds__(256)
void dt_proj(const float* __restrict__ dtbc, const float* __restrict__ dt_w,
             const float* __restrict__ dt_b, float* __restrict__ dtv) {
    int t = blockIdx.x;
    int d = (blockIdx.y << 8) + threadIdx.x;
    __shared__ float r[DTR];
    if (threadIdx.x < DTR) r[threadIdx.x] = dtbc[(size_t)t * 48 + threadIdx.x];
    __syncthreads();
    float s = dt_b[d];
    #pragma unroll
    for (int k = 0; k < DTR; ++k) s = fmaf(r[k], dt_w[k * DI + d], s);
    dtv[(size_t)t * DI + d] = (s > 20.f) ? s : log1pf(expf(s));
}

// ---- selective-scan: one thread per (b,d), 16 states in registers ----
__global__ __launch_bounds__(256)
void ssm_scan(const float* __restrict__ dtv, const float* __restrict__ dtbc,
              const float* __restrict__ xc, const float* __restrict__ A_log,
              const float* __restrict__ D_p, float* __restrict__ y) {
    int d = (blockIdx.x << 8) + threadIdx.x;   // grid.x = 2
    int b = blockIdx.y;                        // grid.y = 16
    float A[DS], h[DS];
    #pragma unroll
    for (int n = 0; n < DS; ++n) { A[n] = -expf(A_log[d * DS + n]); h[n] = 0.f; }
    float Dv = D_p[d];
    for (int l = 0; l < LL; ++l) {
        int t = (b << 8) + l;
        float dt = dtv[(size_t)t * DI + d];
        float xv = xc[(size_t)t * DI + d];
        const float* bc = dtbc + (size_t)t * 48;
        float dtx = dt * xv;
        float acc = 0.f;
        #pragma unroll
        for (int n = 0; n < DS; ++n) {
            float dA = expf(dt * A[n]);
            h[n] = fmaf(dA, h[n], dtx * bc[16 + n]);
            acc = fmaf(h[n], bc[32 + n], acc);
        }
        y[(size_t)t * DI + d] = fmaf(xv, Dv, acc);
    }
}

// ---- gating: y *= silu(z), z = xz[:,512:] ----
__global__ __launch_bounds__(256)
void gate_mul(const float* __restrict__ xz, float* __restrict__ y) {
    int i = blockIdx.x * 256 + threadIdx.x;    // over NTOK*DI
    int t = i >> 9, d = i & (DI - 1);
    float z = xz[(size_t)t * (2 * DI) + DI + d];
    y[i] = y[i] * siluf(z);
}

extern "C" void kernel_launch(void* const* d_in, const int* in_sizes, int n_in,
                              void* d_out, int out_size, void* d_ws, size_t ws_size,
                              hipStream_t stream) {
    const int*   seq      = (const int*)d_in[0];
    const int*   attr     = (const int*)d_in[1];
    const float* item_emb = (const float*)d_in[2];
    const float* attr_emb = (const float*)d_in[3];
    const float* alpha    = (const float*)d_in[4];
    const float* ln_s     = (const float*)d_in[5];
    const float* ln_b     = (const float*)d_in[6];
    const float* in_w     = (const float*)d_in[7];
    const float* conv_w   = (const float*)d_in[8];
    const float* conv_b   = (const float*)d_in[9];
    const float* xp_w     = (const float*)d_in[10];
    const float* dt_w     = (const float*)d_in[11];
    const float* dt_b     = (const float*)d_in[12];
    const float* A_log    = (const float*)d_in[13];
    const float* D_p      = (const float*)d_in[14];
    const float* out_w    = (const float*)d_in[15];
    const float* nrm_s    = (const float*)d_in[16];
    const float* nrm_b    = (const float*)d_in[17];
    const float* head_w   = (const float*)d_in[18];
    float* out = (float*)d_out;

    float* ws   = (float*)d_ws;
    float* x    = ws;                    // 4096*256
    float* xln  = x    + (size_t)NTOK * DM;
    float* xz   = xln  + (size_t)NTOK * DM;     // 4096*1024
    float* xc   = xz   + (size_t)NTOK * 1024;   // 4096*512
    float* dtbc = xc   + (size_t)NTOK * DI;     // 4096*48
    float* dtv  = dtbc + (size_t)NTOK * 48;     // 4096*512
    float* yb   = dtv  + (size_t)NTOK * DI;     // 4096*512

    embed_holo_ln<<<NTOK, 256, 0, stream>>>(seq, attr, item_emb, attr_emb, alpha, ln_s, ln_b, x);

    for (int l = 0; l < 4; ++l) {
        ln_layer<<<NTOK, 256, 0, stream>>>(x, nrm_s + l * DM, nrm_b + l * DM, xln);
        gemm_f32<false><<<dim3(1024 / 128, NTOK / 128), 256, 0, stream>>>(
            xln, in_w + (size_t)l * DM * 1024, xz, NTOK, 1024, DM);
        conv_silu<<<dim3(NTOK, 2), 256, 0, stream>>>(
            xz, conv_w + (size_t)l * DI * 4, conv_b + (size_t)l * DI, xc);
        gemm_f32<false><<<dim3(1, NTOK / 128), 256, 0, stream>>>(
            xc, xp_w + (size_t)l * DI * 48, dtbc, NTOK, 48, DI);
        dt_proj<<<dim3(NTOK, 2), 256, 0, stream>>>(
            dtbc, dt_w + (size_t)l * DTR * DI, dt_b + (size_t)l * DI, dtv);
        ssm_scan<<<dim3(2, BB), 256, 0, stream>>>(
            dtv, dtbc, xc, A_log + (size_t)l * DI * DS, D_p + (size_t)l * DI, yb);
        gate_mul<<<(NTOK * DI) / 256, 256, 0, stream>>>(xz, yb);
        gemm_f32<true><<<dim3(DM / 128, NTOK / 128), 256, 0, stream>>>(
            yb, out_w + (size_t)l * DI * DM, x, NTOK, DM, DI);
    }

    gemm_f32<false><<<dim3((30000 + 127) / 128, NTOK / 128), 256, 0, stream>>>(
        x, head_w, out, NTOK, 30000, DM);
}

// Round 2
// 2661.206 us; speedup vs baseline: 1.3440x; 1.3440x over previous
//
#include <hip/hip_runtime.h>
#include <hip/hip_bf16.h>
#include <math.h>

#define BB 16
#define LL 256
#define DM 256
#define DI 512
#define DS 16
#define DTR 16
#define NTOK (BB*LL)
#define LN_EPS 1e-5f

typedef __attribute__((ext_vector_type(8))) short bf16x8;
typedef __attribute__((ext_vector_type(4))) float f32x4;
typedef __attribute__((ext_vector_type(4))) unsigned int u32x4;

__device__ __forceinline__ float siluf(float x) { return x / (1.f + expf(-x)); }

__device__ __forceinline__ unsigned short f2bf(float f) {
    union { float f; unsigned int u; } x; x.f = f;
    unsigned int r = x.u + 0x7fffu + ((x.u >> 16) & 1u);
    return (unsigned short)(r >> 16);
}
__device__ __forceinline__ float bf2f(unsigned short h) {
    union { unsigned int u; float f; } x; x.u = ((unsigned int)h) << 16; return x.f;
}

// ---- block reduce (sum, sumsq) over 256 threads ----
__device__ __forceinline__ void block_reduce2(float& s, float& s2, float* red) {
    #pragma unroll
    for (int off = 32; off; off >>= 1) {
        s  += __shfl_down(s,  off);
        s2 += __shfl_down(s2, off);
    }
    int wid = threadIdx.x >> 6;
    if ((threadIdx.x & 63) == 0) { red[wid*2] = s; red[wid*2+1] = s2; }
    __syncthreads();
    s  = red[0] + red[2] + red[4] + red[6];
    s2 = red[1] + red[3] + red[5] + red[7];
}

// ---- fused embedding gather + holographic bind (direct circular conv) + layernorm ----
__global__ __launch_bounds__(256)
void embed_holo_ln(const int* __restrict__ seq, const int* __restrict__ attr,
                   const float* __restrict__ item_emb, const float* __restrict__ attr_emb,
                   const float* __restrict__ alpha_p, const float* __restrict__ ln_s,
                   const float* __restrict__ ln_b, float* __restrict__ x) {
    int t = blockIdx.x;
    int k = threadIdx.x;
    __shared__ float ei[DM], ea[DM];
    __shared__ float red[8];
    int si = seq[t], ai = attr[t];
    ei[k] = (si == 0) ? 0.f : item_emb[(size_t)si * DM + k];
    ea[k] = (ai == 0) ? 0.f : attr_emb[(size_t)ai * DM + k];
    __syncthreads();
    float conv = 0.f;
    #pragma unroll 8
    for (int j = 0; j < DM; ++j)
        conv = fmaf(ei[j], ea[(k - j) & (DM - 1)], conv);
    float v = fmaf(alpha_p[0] * 0.0625f, conv, ei[k]);
    float s = v, s2 = v * v;
    block_reduce2(s, s2, red);
    float m  = s * (1.f / DM);
    float var = s2 * (1.f / DM) - m * m;
    x[(size_t)t * DM + k] = (v - m) * rsqrtf(var + LN_EPS) * ln_s[k] + ln_b[k];
}

// ---- layernorm + bf16-split write: Ap[t][0:256]=hi, [256:512]=hi, [512:768]=lo ----
__global__ __launch_bounds__(256)
void ln_split(const float* __restrict__ in, const float* __restrict__ sc,
              const float* __restrict__ bi, unsigned short* __restrict__ Ap) {
    int t = blockIdx.x, k = threadIdx.x;
    __shared__ float red[8];
    float v = in[(size_t)t * DM + k];
    float s = v, s2 = v * v;
    block_reduce2(s, s2, red);
    float m  = s * (1.f / DM);
    float var = s2 * (1.f / DM) - m * m;
    float o = (v - m) * rsqrtf(var + LN_EPS) * sc[k] + bi[k];
    unsigned short hi = f2bf(o), lo = f2bf(o - bf2f(hi));
    size_t base = (size_t)t * (3 * DM);
    Ap[base + k] = hi; Ap[base + DM + k] = hi; Ap[base + 2 * DM + k] = lo;
}

// ---- weight convert: W[K][N] fp32 -> Bt[Npad][3K] bf16, layout [hi|lo|hi], transposed ----
__global__ __launch_bounds__(256)
void cvt_B(const float* __restrict__ W, unsigned short* __restrict__ Bt, int K, int N) {
    int k0 = blockIdx.x * 64, n0 = blockIdx.y * 64;
    int K3 = 3 * K;
    __shared__ float tile[64][65];
    int tid = threadIdx.x;
    #pragma unroll
    for (int i = 0; i < 16; ++i) {
        int idx = tid + i * 256;
        int r = idx >> 6, c = idx & 63;
        int n = n0 + c;
        tile[r][c] = (n < N) ? W[(size_t)(k0 + r) * N + n] : 0.f;
    }
    __syncthreads();
    int nn = tid >> 2, kb = (tid & 3) * 16;
    alignas(16) unsigned short hv[16], lv[16];
    #pragma unroll
    for (int j = 0; j < 16; ++j) {
        float v = tile[kb + j][nn];
        hv[j] = f2bf(v); lv[j] = f2bf(v - bf2f(hv[j]));
    }
    size_t base = (size_t)(n0 + nn) * K3 + k0 + kb;
    *(u32x4*)&Bt[base]           = *(u32x4*)&hv[0];
    *(u32x4*)&Bt[base + 8]       = *(u32x4*)&hv[8];
    *(u32x4*)&Bt[base + K]       = *(u32x4*)&lv[0];
    *(u32x4*)&Bt[base + K + 8]   = *(u32x4*)&lv[8];
    *(u32x4*)&Bt[base + 2*K]     = *(u32x4*)&hv[0];
    *(u32x4*)&Bt[base + 2*K + 8] = *(u32x4*)&hv[8];
}

// ---- activation convert for head: x[4096][256] fp32 -> Ap[4096][768] [hi|hi|lo] ----
__global__ __launch_bounds__(256)
void cvt_A(const float* __restrict__ X, unsigned short* __restrict__ Ap) {
    int i = blockIdx.x * 256 + threadIdx.x;          // over NTOK*DM/8
    int t = i >> 5, kc = (i & 31) * 8;
    const float4* X4 = (const float4*)X;
    float4 v0 = X4[(size_t)i * 2], v1 = X4[(size_t)i * 2 + 1];
    float vv[8] = { v0.x, v0.y, v0.z, v0.w, v1.x, v1.y, v1.z, v1.w };
    alignas(16) unsigned short hv[8], lv[8];
    #pragma unroll
    for (int j = 0; j < 8; ++j) { hv[j] = f2bf(vv[j]); lv[j] = f2bf(vv[j] - bf2f(hv[j])); }
    size_t base = (size_t)t * 768 + kc;
    *(u32x4*)&Ap[base]       = *(u32x4*)&hv[0];
    *(u32x4*)&Ap[base + 256] = *(u32x4*)&hv[0];
    *(u32x4*)&Ap[base + 512] = *(u32x4*)&lv[0];
}

// ---- bf16 MFMA GEMM (m97 recipe): C[M][N] (+)= A[M][K3] @ Bt[Npad][K3]^T ----
// 128x128 tile, 256 thr = 4 waves, each wave 64x64 (4x4 frags 16x16), K-step 32.
template<bool ACC>
__global__ __launch_bounds__(256)
void gemm_bf16t(const unsigned short* __restrict__ A, const unsigned short* __restrict__ Bt,
                float* __restrict__ C, int N, int K3) {
    __shared__ unsigned short sA[128 * 32];
    __shared__ unsigned short sB[128 * 32];
    int tid = threadIdx.x, lane = tid & 63, w = tid >> 6;
    int wr = w >> 1, wc = w & 1;
    int row0 = blockIdx.y * 128, col0 = blockIdx.x * 128;
    f32x4 acc[4][4] = {};
    int rA = lane >> 2;               // 0..15
    int kc = (lane & 3) * 8;
    for (int k0 = 0; k0 < K3; k0 += 32) {
        #pragma unroll
        for (int i = 0; i < 2; ++i) {
            int rr = (w * 2 + i) * 16 + rA;
            const unsigned short* ga = A  + (size_t)(row0 + rr) * K3 + k0 + kc;
            const unsigned short* gb = Bt + (size_t)(col0 + rr) * K3 + k0 + kc;
            __builtin_amdgcn_global_load_lds(
                (const __attribute__((address_space(1))) unsigned int*)ga,
                (__attribute__((address_space(3))) unsigned int*)(sA + (w * 2 + i) * 512), 16, 0, 0);
            __builtin_amdgcn_global_load_lds(
                (const __attribute__((address_space(1))) unsigned int*)gb,
                (__attribute__((address_space(3))) unsigned int*)(sB + (w * 2 + i) * 512), 16, 0, 0);
        }
        __syncthreads();
        bf16x8 av[4], bv[4];
        #pragma unroll
        for (int m = 0; m < 4; ++m)
            av[m] = *(const bf16x8*)(sA + (wr * 64 + m * 16 + (lane & 15)) * 32 + (lane >> 4) * 8);
        #pragma unroll
        for (int n = 0; n < 4; ++n)
            bv[n] = *(const bf16x8*)(sB + (wc * 64 + n * 16 + (lane & 15)) * 32 + (lane >> 4) * 8);
        #pragma unroll
        for (int m = 0; m < 4; ++m)
            #pragma unroll
            for (int n = 0; n < 4; ++n)
                acc[m][n] = __builtin_amdgcn_mfma_f32_16x16x32_bf16(av[m], bv[n], acc[m][n], 0, 0, 0);
        __syncthreads();
    }
    #pragma unroll
    for (int m = 0; m < 4; ++m) {
        int rg = row0 + wr * 64 + m * 16 + (lane >> 4) * 4;
        #pragma unroll
        for (int n = 0; n < 4; ++n) {
            int cg = col0 + wc * 64 + n * 16 + (lane & 15);
            if (cg < N) {
                float* p = C + (size_t)rg * N + cg;
                #pragma unroll
                for (int r = 0; r < 4; ++r) {
                    if (ACC) p[(size_t)r * N] += acc[m][n][r];
                    else     p[(size_t)r * N]  = acc[m][n][r];
                }
            }
        }
    }
}

// ---- causal depthwise conv (width 4) + bias + silu ----
__global__ __launch_bounds__(256)
void conv_silu(const float* __restrict__ xz, const float* __restrict__ w,
               const float* __restrict__ cb, float* __restrict__ xc) {
    int t = blockIdx.x;
    int d = (blockIdx.y << 8) + threadIdx.x;
    int l = t & (LL - 1);
    float acc = cb[d];
    #pragma unroll
    for (int tt = 0; tt < 4; ++tt) {
        int ls = l - 3 + tt;
        if (ls >= 0) acc = fmaf(xz[(size_t)(t - 3 + tt) * (2 * DI) + d], w[d * 4 + tt], acc);
    }
    xc[(size_t)t * DI + d] = siluf(acc);
}

// ---- skinny projection: dtbc[NTOK][48] = xc[NTOK][512] @ xp_w[512][48] ----
__global__ __launch_bounds__(256)
void xp_proj(const float* __restrict__ xc, const float* __restrict__ W, float* __restrict__ out) {
    int t0 = blockIdx.x * 16;
    __shared__ float As[16][516];
    int tid = threadIdx.x;
    const float4* src = (const float4*)(xc + (size_t)t0 * DI);
    #pragma unroll
    for (int i = 0; i < 8; ++i) {
        int idx = tid + i * 256;
        int tok = idx >> 7, c4 = idx & 127;
        float4 v = src[(size_t)tok * 128 + c4];
        As[tok][c4*4] = v.x; As[tok][c4*4+1] = v.y; As[tok][c4*4+2] = v.z; As[tok][c4*4+3] = v.w;
    }
    __syncthreads();
    int tok = tid >> 4, cj = tid & 15;
    float a0 = 0.f, a1 = 0.f, a2 = 0.f;
    for (int k = 0; k < DI; ++k) {
        float a = As[tok][k];
        a0 = fmaf(a, W[k * 48 + cj],      a0);
        a1 = fmaf(a, W[k * 48 + cj + 16], a1);
        a2 = fmaf(a, W[k * 48 + cj + 32], a2);
    }
    size_t base = (size_t)(t0 + tok) * 48;
    out[base + cj] = a0; out[base + cj + 16] = a1; out[base + cj + 32] = a2;
}

// ---- selective-scan with fused dt-projection; 64-thr blocks over 128 CUs ----
__global__ __launch_bounds__(64)
void ssm_scan(const float* __restrict__ dtbc, const float* __restrict__ xc,
              const float* __restrict__ dt_w, const float* __restrict__ dt_b,
              const float* __restrict__ A_log, const float* __restrict__ D_p,
              float* __restrict__ y) {
    int d = blockIdx.x * 64 + threadIdx.x;
    int b = blockIdx.y;
    float A[DS], h[DS], W[DTR];
    #pragma unroll
    for (int n = 0; n < DS; ++n) { A[n] = -expf(A_log[d * DS + n]); h[n] = 0.f; }
    #pragma unroll
    for (int k = 0; k < DTR; ++k) W[k] = dt_w[k * DI + d];
    float bias = dt_b[d], Dv = D_p[d];
    for (int l = 0; l < LL; ++l) {
        int t = (b << 8) + l;
        const float* r = dtbc + (size_t)t * 48;
        float s = bias;
        #pragma unroll
        for (int k = 0; k < DTR; ++k) s = fmaf(r[k], W[k], s);
        float dt = (s > 20.f) ? s : log1pf(expf(s));
        float xv = xc[(size_t)t * DI + d];
        float dtx = dt * xv, accv = 0.f;
        #pragma unroll
        for (int n = 0; n < DS; ++n) {
            float dA = expf(dt * A[n]);
            h[n] = fmaf(dA, h[n], dtx * r[DTR + n]);
            accv = fmaf(h[n], r[DTR + DS + n], accv);
        }
        y[(size_t)t * DI + d] = fmaf(xv, Dv, accv);
    }
}

// ---- gating + bf16-split write: Yp[t][0:512]=hi,[512:1024]=hi,[1024:1536]=lo ----
__global__ __launch_bounds__(256)
void gate_split(const float* __restrict__ xz, const float* __restrict__ y,
                unsigned short* __restrict__ Yp) {
    int i = blockIdx.x * 256 + threadIdx.x;   // NTOK*DI
    int t = i >> 9, d = i & (DI - 1);
    float g = y[i] * siluf(xz[(size_t)t * (2 * DI) + DI + d]);
    unsigned short hi = f2bf(g), lo = f2bf(g - bf2f(hi));
    size_t base = (size_t)t * (3 * DI);
    Yp[base + d] = hi; Yp[base + DI + d] = hi; Yp[base + 2 * DI + d] = lo;
}

extern "C" void kernel_launch(void* const* d_in, const int* in_sizes, int n_in,
                              void* d_out, int out_size, void* d_ws, size_t ws_size,
                              hipStream_t stream) {
    const int*   seq      = (const int*)d_in[0];
    const int*   attr     = (const int*)d_in[1];
    const float* item_emb = (const float*)d_in[2];
    const float* attr_emb = (const float*)d_in[3];
    const float* alpha    = (const float*)d_in[4];
    const float* ln_s     = (const float*)d_in[5];
    const float* ln_b     = (const float*)d_in[6];
    const float* in_w     = (const float*)d_in[7];
    const float* conv_w   = (const float*)d_in[8];
    const float* conv_b   = (const float*)d_in[9];
    const float* xp_w     = (const float*)d_in[10];
    const float* dt_w     = (const float*)d_in[11];
    const float* dt_b     = (const float*)d_in[12];
    const float* A_log    = (const float*)d_in[13];
    const float* D_p      = (const float*)d_in[14];
    const float* out_w    = (const float*)d_in[15];
    const float* nrm_s    = (const float*)d_in[16];
    const float* nrm_b    = (const float*)d_in[17];
    const float* head_w   = (const float*)d_in[18];
    float* out = (float*)d_out;

    // ---- workspace layout (bytes) ----
    char* w8 = (char*)d_ws;
    float*          x    = (float*)(w8);                       //  4,194,304
    unsigned short* Ap   = (unsigned short*)(w8 + 4194304);    //  6,291,456  (A' for LN and head)
    char*           U    = w8 + 4194304 + 6291456;             //  union region
    // layer mode inside U:
    float*          xz   = (float*)(U);                        // 16,777,216
    float*          xc   = (float*)(U + 16777216);             //  8,388,608
    float*          dtbc = (float*)(U + 25165824);             //    786,432
    float*          yb   = (float*)(U + 25952256);             //  8,388,608
    unsigned short* Yp   = (unsigned short*)(U + 34340864);    // 12,582,912 -> U end 46,923,776
    // head mode inside U (layer buffers dead by then):
    unsigned short* Bth  = (unsigned short*)(U);               // 30080*768*2 = 46,202,880
    unsigned short* Btin = (unsigned short*)(w8 + 4194304 + 6291456 + 46923776);            // 1,572,864
    unsigned short* Btout= (unsigned short*)(w8 + 4194304 + 6291456 + 46923776 + 1572864);  //   786,432

    embed_holo_ln<<<NTOK, 256, 0, stream>>>(seq, attr, item_emb, attr_emb, alpha, ln_s, ln_b, x);

    for (int l = 0; l < 4; ++l) {
        ln_split<<<NTOK, 256, 0, stream>>>(x, nrm_s + l * DM, nrm_b + l * DM, Ap);
        cvt_B<<<dim3(4, 16), 256, 0, stream>>>(in_w + (size_t)l * DM * 1024, Btin, DM, 1024);
        gemm_bf16t<false><<<dim3(8, 32), 256, 0, stream>>>(Ap, Btin, xz, 1024, 3 * DM);
        conv_silu<<<dim3(NTOK, 2), 256, 0, stream>>>(
            xz, conv_w + (size_t)l * DI * 4, conv_b + (size_t)l * DI, xc);
        xp_proj<<<NTOK / 16, 256, 0, stream>>>(xc, xp_w + (size_t)l * DI * 48, dtbc);
        ssm_scan<<<dim3(DI / 64, BB), 64, 0, stream>>>(
            dtbc, xc, dt_w + (size_t)l * DTR * DI, dt_b + (size_t)l * DI,
            A_log + (size_t)l * DI * DS, D_p + (size_t)l * DI, yb);
        gate_split<<<(NTOK * DI) / 256, 256, 0, stream>>>(xz, yb, Yp);
        cvt_B<<<dim3(8, 4), 256, 0, stream>>>(out_w + (size_t)l * DI * DM, Btout, DI, DM);
        gemm_bf16t<true><<<dim3(2, 32), 256, 0, stream>>>(Yp, Btout, x, DM, 3 * DI);
    }

    cvt_A<<<(NTOK * DM / 8) / 256, 256, 0, stream>>>(x, Ap);
    cvt_B<<<dim3(4, 470), 256, 0, stream>>>(head_w, Bth, DM, 30000);
    gemm_bf16t<false><<<dim3(235, 32), 256, 0, stream>>>(Ap, Bth, out, 30000, 3 * DM);
}

// Round 8
// 1913.938 us; speedup vs baseline: 1.8687x; 1.3904x over previous
//
#include <hip/hip_runtime.h>
#include <hip/hip_bf16.h>
#include <math.h>

#define BB 16
#define LL 256
#define DM 256
#define DI 512
#define DS 16
#define DTR 16
#define NTOK (BB*LL)
#define LN_EPS 1e-5f

typedef __attribute__((ext_vector_type(8))) short bf16x8;
typedef __attribute__((ext_vector_type(4))) float f32x4;
typedef __attribute__((ext_vector_type(4))) unsigned int u32x4;

__device__ __forceinline__ float siluf(float x) { return x / (1.f + expf(-x)); }

__device__ __forceinline__ unsigned short f2bf(float f) {
    union { float f; unsigned int u; } x; x.f = f;
    unsigned int r = x.u + 0x7fffu + ((x.u >> 16) & 1u);
    return (unsigned short)(r >> 16);
}
__device__ __forceinline__ float bf2f(unsigned short h) {
    union { unsigned int u; float f; } x; x.u = ((unsigned int)h) << 16; return x.f;
}

__device__ __forceinline__ void block_reduce2(float& s, float& s2, float* red) {
    #pragma unroll
    for (int off = 32; off; off >>= 1) {
        s  += __shfl_down(s,  off);
        s2 += __shfl_down(s2, off);
    }
    int wid = threadIdx.x >> 6;
    if ((threadIdx.x & 63) == 0) { red[wid*2] = s; red[wid*2+1] = s2; }
    __syncthreads();
    s  = red[0] + red[2] + red[4] + red[6];
    s2 = red[1] + red[3] + red[5] + red[7];
}

// ---- fused embedding gather + circular-conv bind + layernorm ----
__global__ __launch_bounds__(256)
void embed_holo_ln(const int* __restrict__ seq, const int* __restrict__ attr,
                   const float* __restrict__ item_emb, const float* __restrict__ attr_emb,
                   const float* __restrict__ alpha_p, const float* __restrict__ ln_s,
                   const float* __restrict__ ln_b, float* __restrict__ x) {
    int t = blockIdx.x;
    int k = threadIdx.x;
    __shared__ float ei[DM], ea[DM];
    __shared__ float red[8];
    int si = seq[t], ai = attr[t];
    ei[k] = (si == 0) ? 0.f : item_emb[(size_t)si * DM + k];
    ea[k] = (ai == 0) ? 0.f : attr_emb[(size_t)ai * DM + k];
    __syncthreads();
    float c0 = 0.f, c1 = 0.f, c2 = 0.f, c3 = 0.f;
    #pragma unroll 8
    for (int j = 0; j < DM; j += 4) {
        c0 = fmaf(ei[j],   ea[(k - j)     & 255], c0);
        c1 = fmaf(ei[j+1], ea[(k - j - 1) & 255], c1);
        c2 = fmaf(ei[j+2], ea[(k - j - 2) & 255], c2);
        c3 = fmaf(ei[j+3], ea[(k - j - 3) & 255], c3);
    }
    float conv = (c0 + c1) + (c2 + c3);
    float v = fmaf(alpha_p[0] * 0.0625f, conv, ei[k]);
    float s = v, s2 = v * v;
    block_reduce2(s, s2, red);
    float m  = s * (1.f / DM);
    float var = s2 * (1.f / DM) - m * m;
    x[(size_t)t * DM + k] = (v - m) * rsqrtf(var + LN_EPS) * ln_s[k] + ln_b[k];
}

// ---- layernorm + x2 split write: Ap[t][0:256]=hi, [256:512]=hi ----
__global__ __launch_bounds__(256)
void ln_split2(const float* __restrict__ in, const float* __restrict__ sc,
               const float* __restrict__ bi, unsigned short* __restrict__ Ap) {
    int t = blockIdx.x, k = threadIdx.x;
    __shared__ float red[8];
    float v = in[(size_t)t * DM + k];
    float s = v, s2 = v * v;
    block_reduce2(s, s2, red);
    float m  = s * (1.f / DM);
    float var = s2 * (1.f / DM) - m * m;
    float o = (v - m) * rsqrtf(var + LN_EPS) * sc[k] + bi[k];
    unsigned short hi = f2bf(o);
    size_t base = (size_t)t * (2 * DM);
    Ap[base + k] = hi; Ap[base + DM + k] = hi;
}

// ---- weight convert x2: W[K][N] fp32 -> Bt[Npad][2K] bf16, [hi|lo], transposed ----
__global__ __launch_bounds__(256)
void cvt_B2(const float* __restrict__ W, unsigned short* __restrict__ Bt, int K, int N) {
    int k0 = blockIdx.x * 64, n0 = blockIdx.y * 64;
    int K2 = 2 * K;
    __shared__ float tile[64][65];
    int tid = threadIdx.x;
    #pragma unroll
    for (int i = 0; i < 16; ++i) {
        int idx = tid + i * 256;
        int r = idx >> 6, c = idx & 63;
        int n = n0 + c;
        tile[r][c] = (n < N) ? W[(size_t)(k0 + r) * N + n] : 0.f;
    }
    __syncthreads();
    int nn = tid >> 2, kb = (tid & 3) * 16;
    alignas(16) unsigned short hv[16], lv[16];
    #pragma unroll
    for (int j = 0; j < 16; ++j) {
        float v = tile[kb + j][nn];
        hv[j] = f2bf(v); lv[j] = f2bf(v - bf2f(hv[j]));
    }
    size_t base = (size_t)(n0 + nn) * K2 + k0 + kb;
    *(u32x4*)&Bt[base]         = *(u32x4*)&hv[0];
    *(u32x4*)&Bt[base + 8]     = *(u32x4*)&hv[8];
    *(u32x4*)&Bt[base + K]     = *(u32x4*)&lv[0];
    *(u32x4*)&Bt[base + K + 8] = *(u32x4*)&lv[8];
}

// ---- weight convert x3: W[K][N] fp32 -> Bt[Npad][3K] bf16, [hi|lo|hi] ----
__global__ __launch_bounds__(256)
void cvt_B3(const float* __restrict__ W, unsigned short* __restrict__ Bt, int K, int N) {
    int k0 = blockIdx.x * 64, n0 = blockIdx.y * 64;
    int K3 = 3 * K;
    __shared__ float tile[64][65];
    int tid = threadIdx.x;
    #pragma unroll
    for (int i = 0; i < 16; ++i) {
        int idx = tid + i * 256;
        int r = idx >> 6, c = idx & 63;
        int n = n0 + c;
        tile[r][c] = (n < N) ? W[(size_t)(k0 + r) * N + n] : 0.f;
    }
    __syncthreads();
    int nn = tid >> 2, kb = (tid & 3) * 16;
    alignas(16) unsigned short hv[16], lv[16];
    #pragma unroll
    for (int j = 0; j < 16; ++j) {
        float v = tile[kb + j][nn];
        hv[j] = f2bf(v); lv[j] = f2bf(v - bf2f(hv[j]));
    }
    size_t base = (size_t)(n0 + nn) * K3 + k0 + kb;
    *(u32x4*)&Bt[base]           = *(u32x4*)&hv[0];
    *(u32x4*)&Bt[base + 8]       = *(u32x4*)&hv[8];
    *(u32x4*)&Bt[base + K]       = *(u32x4*)&lv[0];
    *(u32x4*)&Bt[base + K + 8]   = *(u32x4*)&lv[8];
    *(u32x4*)&Bt[base + 2*K]     = *(u32x4*)&hv[0];
    *(u32x4*)&Bt[base + 2*K + 8] = *(u32x4*)&hv[8];
}

// ---- head activation convert x3: x[4096][256] -> Ap3[4096][768] [hi|hi|lo] ----
__global__ __launch_bounds__(256)
void cvt_A3(const float* __restrict__ X, unsigned short* __restrict__ Ap) {
    int i = blockIdx.x * 256 + threadIdx.x;          // NTOK*DM/8
    int t = i >> 5, kc = (i & 31) * 8;
    const float4* X4 = (const float4*)X;
    float4 v0 = X4[(size_t)i * 2], v1 = X4[(size_t)i * 2 + 1];
    float vv[8] = { v0.x, v0.y, v0.z, v0.w, v1.x, v1.y, v1.z, v1.w };
    alignas(16) unsigned short hv[8], lv[8];
    #pragma unroll
    for (int j = 0; j < 8; ++j) { hv[j] = f2bf(vv[j]); lv[j] = f2bf(vv[j] - bf2f(hv[j])); }
    size_t base = (size_t)t * 768 + kc;
    *(u32x4*)&Ap[base]       = *(u32x4*)&hv[0];
    *(u32x4*)&Ap[base + 256] = *(u32x4*)&hv[0];
    *(u32x4*)&Ap[base + 512] = *(u32x4*)&lv[0];
}

// ---- bf16 MFMA GEMM: C[M][N] (+)= A[M][K] @ Bt[Npad][K]^T (K = split-expanded) ----
template<bool ACC, bool SWZ>
__global__ __launch_bounds__(256)
void gemm_bf16t(const unsigned short* __restrict__ A, const unsigned short* __restrict__ Bt,
                float* __restrict__ C, int N, int K) {
    __shared__ unsigned short sA[128 * 32];
    __shared__ unsigned short sB[128 * 32];
    int tid = threadIdx.x, lane = tid & 63, w = tid >> 6;
    int wr = w >> 1, wc = w & 1;
    int row0, col0;
    if (SWZ) {
        int nwg = gridDim.x * gridDim.y;
        int chunk = nwg >> 3;
        int bid = blockIdx.y * gridDim.x + blockIdx.x;
        int idx = (bid & 7) * chunk + (bid >> 3);
        int rowt = idx % gridDim.y;      // row fastest -> B-panel reuse in XCD L2
        int colt = idx / gridDim.y;
        row0 = rowt * 128; col0 = colt * 128;
    } else {
        row0 = blockIdx.y * 128; col0 = blockIdx.x * 128;
    }
    f32x4 acc[4][4] = {};
    int rA = lane >> 2;
    int kc = (lane & 3) * 8;
    for (int k0 = 0; k0 < K; k0 += 32) {
        #pragma unroll
        for (int i = 0; i < 2; ++i) {
            int rr = (w * 2 + i) * 16 + rA;
            const unsigned short* ga = A  + (size_t)(row0 + rr) * K + k0 + kc;
            const unsigned short* gb = Bt + (size_t)(col0 + rr) * K + k0 + kc;
            __builtin_amdgcn_global_load_lds(
                (const __attribute__((address_space(1))) unsigned int*)ga,
                (__attribute__((address_space(3))) unsigned int*)(sA + (w * 2 + i) * 512), 16, 0, 0);
            __builtin_amdgcn_global_load_lds(
                (const __attribute__((address_space(1))) unsigned int*)gb,
                (__attribute__((address_space(3))) unsigned int*)(sB + (w * 2 + i) * 512), 16, 0, 0);
        }
        __syncthreads();
        bf16x8 av[4], bv[4];
        #pragma unroll
        for (int m = 0; m < 4; ++m)
            av[m] = *(const bf16x8*)(sA + (wr * 64 + m * 16 + (lane & 15)) * 32 + (lane >> 4) * 8);
        #pragma unroll
        for (int n = 0; n < 4; ++n)
            bv[n] = *(const bf16x8*)(sB + (wc * 64 + n * 16 + (lane & 15)) * 32 + (lane >> 4) * 8);
        #pragma unroll
        for (int m = 0; m < 4; ++m)
            #pragma unroll
            for (int n = 0; n < 4; ++n)
                acc[m][n] = __builtin_amdgcn_mfma_f32_16x16x32_bf16(av[m], bv[n], acc[m][n], 0, 0, 0);
        __syncthreads();
    }
    #pragma unroll
    for (int m = 0; m < 4; ++m) {
        int rg = row0 + wr * 64 + m * 16 + (lane >> 4) * 4;
        #pragma unroll
        for (int n = 0; n < 4; ++n) {
            int cg = col0 + wc * 64 + n * 16 + (lane & 15);
            if (cg < N) {
                float* p = C + (size_t)rg * N + cg;
                #pragma unroll
                for (int r = 0; r < 4; ++r) {
                    if (ACC)      p[(size_t)r * N] += acc[m][n][r];
                    else if (SWZ) __builtin_nontemporal_store(acc[m][n][r], p + (size_t)r * N);
                    else          p[(size_t)r * N]  = acc[m][n][r];
                }
            }
        }
    }
}

// ---- causal depthwise conv + bias + silu; writes fp32 xc AND x3-split Xc3 ----
__global__ __launch_bounds__(256)
void conv_silu(const float* __restrict__ xz, const float* __restrict__ w,
               const float* __restrict__ cb, float* __restrict__ xc,
               unsigned short* __restrict__ Xc3) {
    int t = blockIdx.x;
    int d = (blockIdx.y << 8) + threadIdx.x;
    int l = t & (LL - 1);
    float acc = cb[d];
    #pragma unroll
    for (int tt = 0; tt < 4; ++tt) {
        int ls = l - 3 + tt;
        if (ls >= 0) acc = fmaf(xz[(size_t)(t - 3 + tt) * (2 * DI) + d], w[d * 4 + tt], acc);
    }
    float v = siluf(acc);
    xc[(size_t)t * DI + d] = v;
    unsigned short hi = f2bf(v), lo = f2bf(v - bf2f(hi));
    size_t base = (size_t)t * (3 * DI);
    Xc3[base + d] = hi; Xc3[base + DI + d] = hi; Xc3[base + 2 * DI + d] = lo;
}

// ---- scan pass 1: per (b, chunk) local recurrence from h=0; emits y_partial, P, h_end ----
#define NCH 4
#define TCH 64
__global__ __launch_bounds__(256)
void scan_p1(const float* __restrict__ dtbc, const float* __restrict__ xc,
             const float* __restrict__ dt_w, const float* __restrict__ dt_b,
             const float* __restrict__ A_log, const float* __restrict__ D_p,
             float* __restrict__ y, float* __restrict__ Hend, float* __restrict__ Pb) {
    int d = blockIdx.x * 256 + threadIdx.x;
    int b = blockIdx.y, c = blockIdx.z;
    int t0 = b * LL + c * TCH;
    __shared__ float rs[TCH * 48];
    const float* src = dtbc + (size_t)t0 * 48;
    #pragma unroll
    for (int i = 0; i < 12; ++i) rs[threadIdx.x + i * 256] = src[threadIdx.x + i * 256];
    __syncthreads();
    float Av[DS], h[DS], P[DS], Wd[DTR];
    #pragma unroll
    for (int n = 0; n < DS; ++n) { Av[n] = -expf(A_log[d * DS + n]); h[n] = 0.f; P[n] = 1.f; }
    #pragma unroll
    for (int k = 0; k < DTR; ++k) Wd[k] = dt_w[k * DI + d];
    float bias = dt_b[d], Dv = D_p[d];
    for (int t = 0; t < TCH; ++t) {
        const float* r = rs + t * 48;
        float s = bias;
        #pragma unroll
        for (int k = 0; k < DTR; ++k) s = fmaf(r[k], Wd[k], s);
        float dt = (s > 20.f) ? s : log1pf(expf(s));
        float xv = xc[(size_t)(t0 + t) * DI + d];
        float dtx = dt * xv, acc = 0.f;
        #pragma unroll
        for (int n = 0; n < DS; ++n) {
            float dA = expf(dt * Av[n]);
            h[n] = fmaf(dA, h[n], dtx * r[DTR + n]);
            P[n] *= dA;
            acc = fmaf(h[n], r[DTR + DS + n], acc);
        }
        y[(size_t)(t0 + t) * DI + d] = fmaf(xv, Dv, acc);
    }
    size_t sb = ((size_t)(b * NCH + c) * DI + d) * DS;
    #pragma unroll
    for (int n = 0; n < DS; ++n) { Hend[sb + n] = h[n]; Pb[sb + n] = P[n]; }
}

// ---- scan pass 2: stitch carries into chunks 1..3 ----
__global__ __launch_bounds__(256)
void scan_p2(const float* __restrict__ dtbc,
             const float* __restrict__ dt_w, const float* __restrict__ dt_b,
             const float* __restrict__ A_log,
             float* __restrict__ y, const float* __restrict__ Hend,
             const float* __restrict__ Pb) {
    int d = blockIdx.x * 256 + threadIdx.x;
    int b = blockIdx.y, c = blockIdx.z + 1;
    int t0 = b * LL + c * TCH;
    __shared__ float rs[TCH * 48];
    const float* src = dtbc + (size_t)t0 * 48;
    #pragma unroll
    for (int i = 0; i < 12; ++i) rs[threadIdx.x + i * 256] = src[threadIdx.x + i * 256];
    __syncthreads();
    float Av[DS], g[DS], Wd[DTR];
    #pragma unroll
    for (int n = 0; n < DS; ++n) Av[n] = -expf(A_log[d * DS + n]);
    #pragma unroll
    for (int k = 0; k < DTR; ++k) Wd[k] = dt_w[k * DI + d];
    float bias = dt_b[d];
    // g = true h at end of chunk c-1
    {
        size_t sb0 = ((size_t)(b * NCH + 0) * DI + d) * DS;
        #pragma unroll
        for (int n = 0; n < DS; ++n) g[n] = Hend[sb0 + n];
        for (int cc = 1; cc < c; ++cc) {
            size_t sb = ((size_t)(b * NCH + cc) * DI + d) * DS;
            #pragma unroll
            for (int n = 0; n < DS; ++n) g[n] = fmaf(Pb[sb + n], g[n], Hend[sb + n]);
        }
    }
    for (int t = 0; t < TCH; ++t) {
        const float* r = rs + t * 48;
        float s = bias;
        #pragma unroll
        for (int k = 0; k < DTR; ++k) s = fmaf(r[k], Wd[k], s);
        float dt = (s > 20.f) ? s : log1pf(expf(s));
        float acc = 0.f;
        #pragma unroll
        for (int n = 0; n < DS; ++n) {
            g[n] *= expf(dt * Av[n]);
            acc = fmaf(g[n], r[DTR + DS + n], acc);
        }
        size_t yi = (size_t)(t0 + t) * DI + d;
        y[yi] += acc;
    }
}

// ---- gating + x2 split write: Yp[t][0:512]=hi,[512:1024]=hi ----
__global__ __launch_bounds__(256)
void gate_split2(const float* __restrict__ xz, const float* __restrict__ y,
                 unsigned short* __restrict__ Yp) {
    int i = blockIdx.x * 256 + threadIdx.x;   // NTOK*DI
    int t = i >> 9, d = i & (DI - 1);
    float g = y[i] * siluf(xz[(size_t)t * (2 * DI) + DI + d]);
    unsigned short hi = f2bf(g);
    size_t base = (size_t)t * (2 * DI);
    Yp[base + d] = hi; Yp[base + DI + d] = hi;
}

extern "C" void kernel_launch(void* const* d_in, const int* in_sizes, int n_in,
                              void* d_out, int out_size, void* d_ws, size_t ws_size,
                              hipStream_t stream) {
    const int*   seq      = (const int*)d_in[0];
    const int*   attr     = (const int*)d_in[1];
    const float* item_emb = (const float*)d_in[2];
    const float* attr_emb = (const float*)d_in[3];
    const float* alpha    = (const float*)d_in[4];
    const float* ln_s     = (const float*)d_in[5];
    const float* ln_b     = (const float*)d_in[6];
    const float* in_w     = (const float*)d_in[7];
    const float* conv_w   = (const float*)d_in[8];
    const float* conv_b   = (const float*)d_in[9];
    const float* xp_w     = (const float*)d_in[10];
    const float* dt_w     = (const float*)d_in[11];
    const float* dt_b     = (const float*)d_in[12];
    const float* A_log    = (const float*)d_in[13];
    const float* D_p      = (const float*)d_in[14];
    const float* out_w    = (const float*)d_in[15];
    const float* nrm_s    = (const float*)d_in[16];
    const float* nrm_b    = (const float*)d_in[17];
    const float* head_w   = (const float*)d_in[18];
    float* out = (float*)d_out;

    // ---- workspace layout (byte offsets; peak 57.3 MB, < 59.8 MB validated earlier) ----
    char* w8 = (char*)d_ws;
    float*          x     = (float*)(w8);                      // 4,194,304 (alive whole run)
    // layer phase:
    unsigned short* Ap    = (unsigned short*)(w8 +  4194304);  // 4,194,304
    float*          Hend  = (float*)(w8 +  4194304);           //   overlays Ap (2 MB)
    float*          Pb    = (float*)(w8 +  6291456);           //   overlays Ap (2 MB)
    float*          xz    = (float*)(w8 +  8388608);           // 16,777,216
    float*          xc    = (float*)(w8 + 25165824);           //  8,388,608
    unsigned short* Xc3   = (unsigned short*)(w8 + 33554432);  // 12,582,912
    unsigned short* Yp    = (unsigned short*)(w8 + 33554432);  //   overlays Xc3 (after xp-gemm)
    float*          yb    = (float*)(w8 + 46137344);           //  8,388,608
    float*          dtbc  = (float*)(w8 + 54525952);           //    786,432
    unsigned short* Btin  = (unsigned short*)(w8 + 55312384);  //  1,048,576
    unsigned short* Btxp  = (unsigned short*)(w8 + 56360960);  //    393,216
    unsigned short* Btout = (unsigned short*)(w8 + 56754176);  //    524,288 -> 57,278,464
    // head phase (everything except x dead):
    unsigned short* Ap3   = (unsigned short*)(w8 +  4194304);  //  6,291,456 -> ends 10,485,760
    unsigned short* Bth   = (unsigned short*)(w8 + 10485760);  // 46,202,880 -> ends 56,688,640

    embed_holo_ln<<<NTOK, 256, 0, stream>>>(seq, attr, item_emb, attr_emb, alpha, ln_s, ln_b, x);

    for (int l = 0; l < 4; ++l) {
        ln_split2<<<NTOK, 256, 0, stream>>>(x, nrm_s + l * DM, nrm_b + l * DM, Ap);
        cvt_B2<<<dim3(4, 16), 256, 0, stream>>>(in_w + (size_t)l * DM * 1024, Btin, DM, 1024);
        gemm_bf16t<false, false><<<dim3(8, 32), 256, 0, stream>>>(Ap, Btin, xz, 1024, 2 * DM);
        conv_silu<<<dim3(NTOK, 2), 256, 0, stream>>>(
            xz, conv_w + (size_t)l * DI * 4, conv_b + (size_t)l * DI, xc, Xc3);
        cvt_B3<<<dim3(8, 2), 256, 0, stream>>>(xp_w + (size_t)l * DI * 48, Btxp, DI, 48);
        gemm_bf16t<false, false><<<dim3(1, 32), 256, 0, stream>>>(Xc3, Btxp, dtbc, 48, 3 * DI);
        scan_p1<<<dim3(2, BB, NCH), 256, 0, stream>>>(
            dtbc, xc, dt_w + (size_t)l * DTR * DI, dt_b + (size_t)l * DI,
            A_log + (size_t)l * DI * DS, D_p + (size_t)l * DI, yb, Hend, Pb);
        scan_p2<<<dim3(2, BB, NCH - 1), 256, 0, stream>>>(
            dtbc, dt_w + (size_t)l * DTR * DI, dt_b + (size_t)l * DI,
            A_log + (size_t)l * DI * DS, yb, Hend, Pb);
        gate_split2<<<(NTOK * DI) / 256, 256, 0, stream>>>(xz, yb, Yp);
        cvt_B2<<<dim3(8, 4), 256, 0, stream>>>(out_w + (size_t)l * DI * DM, Btout, DI, DM);
        gemm_bf16t<true, false><<<dim3(2, 32), 256, 0, stream>>>(Yp, Btout, x, DM, 2 * DI);
    }

    cvt_A3<<<(NTOK * DM / 8) / 256, 256, 0, stream>>>(x, Ap3);
    cvt_B3<<<dim3(4, 470), 256, 0, stream>>>(head_w, Bth, DM, 30000);
    gemm_bf16t<false, true><<<dim3(235, 32), 256, 0, stream>>>(Ap3, Bth, out, 30000, 3 * DM);
}

// Round 11
// 1605.031 us; speedup vs baseline: 2.2284x; 1.1925x over previous
//
#include <hip/hip_runtime.h>
#include <hip/hip_bf16.h>
#include <math.h>

#define BB 16
#define LL 256
#define DM 256
#define DI 512
#define DS 16
#define DTR 16
#define NTOK (BB*LL)
#define LN_EPS 1e-5f
#define NCH 8
#define TCH 32

typedef __attribute__((ext_vector_type(8))) short bf16x8;
typedef __attribute__((ext_vector_type(4))) float f32x4;
typedef __attribute__((ext_vector_type(4))) unsigned int u32x4;

__device__ __forceinline__ float siluf(float x) { return x / (1.f + expf(-x)); }

__device__ __forceinline__ unsigned short f2bf(float f) {
    union { float f; unsigned int u; } x; x.f = f;
    unsigned int r = x.u + 0x7fffu + ((x.u >> 16) & 1u);
    return (unsigned short)(r >> 16);
}
__device__ __forceinline__ float bf2f(unsigned short h) {
    union { unsigned int u; float f; } x; x.u = ((unsigned int)h) << 16; return x.f;
}

__device__ __forceinline__ void block_reduce2(float& s, float& s2, float* red) {
    #pragma unroll
    for (int off = 32; off; off >>= 1) {
        s  += __shfl_down(s,  off);
        s2 += __shfl_down(s2, off);
    }
    int wid = threadIdx.x >> 6;
    if ((threadIdx.x & 63) == 0) { red[wid*2] = s; red[wid*2+1] = s2; }
    __syncthreads();
    s  = red[0] + red[2] + red[4] + red[6];
    s2 = red[1] + red[3] + red[5] + red[7];
}

// ---- device bodies for weight conversion (shared tile = 64*65 floats) ----
__device__ __forceinline__ void cvtB2_body(const float* __restrict__ W, unsigned short* __restrict__ Bt,
                                           int K, int N, int bkx, int bny, float* tile) {
    int k0 = bkx * 64, n0 = bny * 64;
    int K2 = 2 * K;
    int tid = threadIdx.x;
    #pragma unroll
    for (int i = 0; i < 16; ++i) {
        int idx = tid + i * 256;
        int r = idx >> 6, c = idx & 63;
        int n = n0 + c;
        tile[r * 65 + c] = (n < N) ? W[(size_t)(k0 + r) * N + n] : 0.f;
    }
    __syncthreads();
    int nn = tid >> 2, kb = (tid & 3) * 16;
    alignas(16) unsigned short hv[16], lv[16];
    #pragma unroll
    for (int j = 0; j < 16; ++j) {
        float v = tile[(kb + j) * 65 + nn];
        hv[j] = f2bf(v); lv[j] = f2bf(v - bf2f(hv[j]));
    }
    size_t base = (size_t)(n0 + nn) * K2 + k0 + kb;
    *(u32x4*)&Bt[base]         = *(u32x4*)&hv[0];
    *(u32x4*)&Bt[base + 8]     = *(u32x4*)&hv[8];
    *(u32x4*)&Bt[base + K]     = *(u32x4*)&lv[0];
    *(u32x4*)&Bt[base + K + 8] = *(u32x4*)&lv[8];
}

__device__ __forceinline__ void cvtB3_body(const float* __restrict__ W, unsigned short* __restrict__ Bt,
                                           int K, int N, int bkx, int bny, float* tile) {
    int k0 = bkx * 64, n0 = bny * 64;
    int K3 = 3 * K;
    int tid = threadIdx.x;
    #pragma unroll
    for (int i = 0; i < 16; ++i) {
        int idx = tid + i * 256;
        int r = idx >> 6, c = idx & 63;
        int n = n0 + c;
        tile[r * 65 + c] = (n < N) ? W[(size_t)(k0 + r) * N + n] : 0.f;
    }
    __syncthreads();
    int nn = tid >> 2, kb = (tid & 3) * 16;
    alignas(16) unsigned short hv[16], lv[16];
    #pragma unroll
    for (int j = 0; j < 16; ++j) {
        float v = tile[(kb + j) * 65 + nn];
        hv[j] = f2bf(v); lv[j] = f2bf(v - bf2f(hv[j]));
    }
    size_t base = (size_t)(n0 + nn) * K3 + k0 + kb;
    *(u32x4*)&Bt[base]           = *(u32x4*)&hv[0];
    *(u32x4*)&Bt[base + 8]       = *(u32x4*)&hv[8];
    *(u32x4*)&Bt[base + K]       = *(u32x4*)&lv[0];
    *(u32x4*)&Bt[base + K + 8]   = *(u32x4*)&lv[8];
    *(u32x4*)&Bt[base + 2*K]     = *(u32x4*)&hv[0];
    *(u32x4*)&Bt[base + 2*K + 8] = *(u32x4*)&hv[8];
}

// ---- fused embedding gather + circular-conv bind + layernorm ----
__global__ __launch_bounds__(256)
void embed_holo_ln(const int* __restrict__ seq, const int* __restrict__ attr,
                   const float* __restrict__ item_emb, const float* __restrict__ attr_emb,
                   const float* __restrict__ alpha_p, const float* __restrict__ ln_s,
                   const float* __restrict__ ln_b, float* __restrict__ x) {
    int t = blockIdx.x;
    int k = threadIdx.x;
    __shared__ float ei[DM], ea[DM];
    __shared__ float red[8];
    int si = seq[t], ai = attr[t];
    ei[k] = (si == 0) ? 0.f : item_emb[(size_t)si * DM + k];
    ea[k] = (ai == 0) ? 0.f : attr_emb[(size_t)ai * DM + k];
    __syncthreads();
    float c0 = 0.f, c1 = 0.f, c2 = 0.f, c3 = 0.f;
    #pragma unroll 8
    for (int j = 0; j < DM; j += 4) {
        c0 = fmaf(ei[j],   ea[(k - j)     & 255], c0);
        c1 = fmaf(ei[j+1], ea[(k - j - 1) & 255], c1);
        c2 = fmaf(ei[j+2], ea[(k - j - 2) & 255], c2);
        c3 = fmaf(ei[j+3], ea[(k - j - 3) & 255], c3);
    }
    float conv = (c0 + c1) + (c2 + c3);
    float v = fmaf(alpha_p[0] * 0.0625f, conv, ei[k]);
    float s = v, s2 = v * v;
    block_reduce2(s, s2, red);
    float m  = s * (1.f / DM);
    float var = s2 * (1.f / DM) - m * m;
    x[(size_t)t * DM + k] = (v - m) * rsqrtf(var + LN_EPS) * ln_s[k] + ln_b[k];
}

// ---- fused per-layer prep: LN+x2-split (blocks 0..4095), in_w cvt (64), xp_w cvt (16), out_w cvt (32) ----
__global__ __launch_bounds__(256)
void layer_prep(const float* __restrict__ x, const float* __restrict__ sc,
                const float* __restrict__ bi, unsigned short* __restrict__ Ap,
                const float* __restrict__ in_w_l, unsigned short* __restrict__ Btin,
                const float* __restrict__ xp_w_l, unsigned short* __restrict__ Btxp,
                const float* __restrict__ out_w_l, unsigned short* __restrict__ Btout) {
    __shared__ float sh[64 * 65];
    int bid = blockIdx.x;
    if (bid < NTOK) {
        int t = bid, k = threadIdx.x;
        float v = x[(size_t)t * DM + k];
        float s = v, s2 = v * v;
        block_reduce2(s, s2, sh);
        float m  = s * (1.f / DM);
        float var = s2 * (1.f / DM) - m * m;
        float o = (v - m) * rsqrtf(var + LN_EPS) * sc[k] + bi[k];
        unsigned short hi = f2bf(o);
        size_t base = (size_t)t * (2 * DM);
        Ap[base + k] = hi; Ap[base + DM + k] = hi;
    } else if (bid < NTOK + 64) {
        int idx = bid - NTOK;
        cvtB2_body(in_w_l, Btin, DM, 1024, idx & 3, idx >> 2, sh);
    } else if (bid < NTOK + 80) {
        int idx = bid - (NTOK + 64);
        cvtB3_body(xp_w_l, Btxp, DI, 48, idx & 7, idx >> 3, sh);
    } else {
        int idx = bid - (NTOK + 80);
        cvtB2_body(out_w_l, Btout, DI, DM, idx & 7, idx >> 3, sh);
    }
}

// ---- fused head prep: cvt_A3 (blocks 0..511) + head cvt_B3 (1880 blocks) ----
__global__ __launch_bounds__(256)
void head_prep(const float* __restrict__ X, unsigned short* __restrict__ Ap3,
               const float* __restrict__ head_w, unsigned short* __restrict__ Bth) {
    __shared__ float sh[64 * 65];
    int bid = blockIdx.x;
    if (bid < 512) {
        int i = bid * 256 + threadIdx.x;          // NTOK*DM/8
        int t = i >> 5, kc = (i & 31) * 8;
        const f32x4* X4 = (const f32x4*)X;
        f32x4 v0 = X4[(size_t)i * 2], v1 = X4[(size_t)i * 2 + 1];
        float vv[8] = { v0.x, v0.y, v0.z, v0.w, v1.x, v1.y, v1.z, v1.w };
        alignas(16) unsigned short hv[8], lv[8];
        #pragma unroll
        for (int j = 0; j < 8; ++j) { hv[j] = f2bf(vv[j]); lv[j] = f2bf(vv[j] - bf2f(hv[j])); }
        size_t base = (size_t)t * 768 + kc;
        *(u32x4*)&Ap3[base]       = *(u32x4*)&hv[0];
        *(u32x4*)&Ap3[base + 256] = *(u32x4*)&hv[0];
        *(u32x4*)&Ap3[base + 512] = *(u32x4*)&lv[0];
    } else {
        int idx = bid - 512;                       // 1880 blocks: k 4 x n 470
        cvtB3_body(head_w, Bth, DM, 30000, idx & 3, idx >> 2, sh);
    }
}

// ---- bf16 MFMA GEMM: C[M][N] (+)= A[M][K] @ Bt[Npad][K]^T (K = split-expanded) ----
template<bool ACC, bool SWZ>
__global__ __launch_bounds__(256)
void gemm_bf16t(const unsigned short* __restrict__ A, const unsigned short* __restrict__ Bt,
                float* __restrict__ C, int N, int K) {
    __shared__ unsigned short sA[128 * 32];
    __shared__ unsigned short sB[128 * 32];
    int tid = threadIdx.x, lane = tid & 63, w = tid >> 6;
    int wr = w >> 1, wc = w & 1;
    int row0, col0;
    if (SWZ) {
        int nwg = gridDim.x * gridDim.y;
        int chunk = nwg >> 3;
        int bid = blockIdx.y * gridDim.x + blockIdx.x;
        int idx = (bid & 7) * chunk + (bid >> 3);
        int rowt = idx % gridDim.y;      // row fastest -> B-panel reuse in XCD L2
        int colt = idx / gridDim.y;
        row0 = rowt * 128; col0 = colt * 128;
    } else {
        row0 = blockIdx.y * 128; col0 = blockIdx.x * 128;
    }
    f32x4 acc[4][4] = {};
    int rA = lane >> 2;
    int kc = (lane & 3) * 8;
    for (int k0 = 0; k0 < K; k0 += 32) {
        #pragma unroll
        for (int i = 0; i < 2; ++i) {
            int rr = (w * 2 + i) * 16 + rA;
            const unsigned short* ga = A  + (size_t)(row0 + rr) * K + k0 + kc;
            const unsigned short* gb = Bt + (size_t)(col0 + rr) * K + k0 + kc;
            __builtin_amdgcn_global_load_lds(
                (const __attribute__((address_space(1))) unsigned int*)ga,
                (__attribute__((address_space(3))) unsigned int*)(sA + (w * 2 + i) * 512), 16, 0, 0);
            __builtin_amdgcn_global_load_lds(
                (const __attribute__((address_space(1))) unsigned int*)gb,
                (__attribute__((address_space(3))) unsigned int*)(sB + (w * 2 + i) * 512), 16, 0, 0);
        }
        __syncthreads();
        bf16x8 av[4], bv[4];
        #pragma unroll
        for (int m = 0; m < 4; ++m)
            av[m] = *(const bf16x8*)(sA + (wr * 64 + m * 16 + (lane & 15)) * 32 + (lane >> 4) * 8);
        #pragma unroll
        for (int n = 0; n < 4; ++n)
            bv[n] = *(const bf16x8*)(sB + (wc * 64 + n * 16 + (lane & 15)) * 32 + (lane >> 4) * 8);
        #pragma unroll
        for (int m = 0; m < 4; ++m)
            #pragma unroll
            for (int n = 0; n < 4; ++n)
                acc[m][n] = __builtin_amdgcn_mfma_f32_16x16x32_bf16(av[m], bv[n], acc[m][n], 0, 0, 0);
        __syncthreads();
    }
    if constexpr (SWZ) {
        // LDS-transposed epilogue: stage 16x64 tile per wave, store 256B-contiguous row segments
        __shared__ float stg[4][16][68];
        #pragma unroll
        for (int m = 0; m < 4; ++m) {
            #pragma unroll
            for (int n = 0; n < 4; ++n)
                #pragma unroll
                for (int r = 0; r < 4; ++r)
                    stg[w][(lane >> 4) * 4 + r][n * 16 + (lane & 15)] = acc[m][n][r];
            __syncthreads();
            // read back transposed: 16 consecutive lanes cover 64 consecutive cols of ONE row
            int rsub = lane >> 4;            // 0..3
            int c4   = (lane & 15) * 4;      // 0,4,..,60
            #pragma unroll
            for (int rg4 = 0; rg4 < 4; ++rg4) {
                int rr = rg4 * 4 + rsub;
                int rg = row0 + wr * 64 + m * 16 + rr;
                int cg = col0 + wc * 64 + c4;
                if (cg < N)   // N % 4 == 0 -> whole float4 valid
                    __builtin_nontemporal_store(*(const f32x4*)&stg[w][rr][c4],
                                                (f32x4*)(C + (size_t)rg * N + cg));
            }
            __syncthreads();
        }
    } else {
        #pragma unroll
        for (int m = 0; m < 4; ++m) {
            int rg = row0 + wr * 64 + m * 16 + (lane >> 4) * 4;
            #pragma unroll
            for (int n = 0; n < 4; ++n) {
                int cg = col0 + wc * 64 + n * 16 + (lane & 15);
                if (cg < N) {
                    float* p = C + (size_t)rg * N + cg;
                    #pragma unroll
                    for (int r = 0; r < 4; ++r) {
                        if (ACC) p[(size_t)r * N] += acc[m][n][r];
                        else     p[(size_t)r * N]  = acc[m][n][r];
                    }
                }
            }
        }
    }
}

// ---- causal depthwise conv + bias + silu; writes fp32 xc AND x3-split Xc3 ----
__global__ __launch_bounds__(256)
void conv_silu(const float* __restrict__ xz, const float* __restrict__ w,
               const float* __restrict__ cb, float* __restrict__ xc,
               unsigned short* __restrict__ Xc3) {
    int t = blockIdx.x;
    int d = (blockIdx.y << 8) + threadIdx.x;
    int l = t & (LL - 1);
    float acc = cb[d];
    #pragma unroll
    for (int tt = 0; tt < 4; ++tt) {
        int ls = l - 3 + tt;
        if (ls >= 0) acc = fmaf(xz[(size_t)(t - 3 + tt) * (2 * DI) + d], w[d * 4 + tt], acc);
    }
    float v = siluf(acc);
    xc[(size_t)t * DI + d] = v;
    unsigned short hi = f2bf(v), lo = f2bf(v - bf2f(hi));
    size_t base = (size_t)t * (3 * DI);
    Xc3[base + d] = hi; Xc3[base + DI + d] = hi; Xc3[base + 2 * DI + d] = lo;
}

// ---- scan pass 1: per (b,chunk) local recurrence from h=0; chunk 0 also gates+splits ----
__global__ __launch_bounds__(256)
void scan_p1(const float* __restrict__ dtbc, const float* __restrict__ xc,
             const float* __restrict__ xz,
             const float* __restrict__ dt_w, const float* __restrict__ dt_b,
             const float* __restrict__ A_log, const float* __restrict__ D_p,
             float* __restrict__ y, float* __restrict__ Hend, float* __restrict__ Pb,
             unsigned short* __restrict__ Yp) {
    int d = blockIdx.x * 256 + threadIdx.x;
    int b = blockIdx.y, c = blockIdx.z;
    int t0 = b * LL + c * TCH;
    __shared__ float rs[TCH * 48];
    const float* src = dtbc + (size_t)t0 * 48;
    #pragma unroll
    for (int i = 0; i < 6; ++i) rs[threadIdx.x + i * 256] = src[threadIdx.x + i * 256];
    __syncthreads();
    float Av[DS], h[DS], P[DS], Wd[DTR];
    #pragma unroll
    for (int n = 0; n < DS; ++n) { Av[n] = -expf(A_log[d * DS + n]); h[n] = 0.f; P[n] = 1.f; }
    #pragma unroll
    for (int k = 0; k < DTR; ++k) Wd[k] = dt_w[k * DI + d];
    float bias = dt_b[d], Dv = D_p[d];
    for (int t = 0; t < TCH; ++t) {
        const float* r = rs + t * 48;
        float s = bias;
        #pragma unroll
        for (int k = 0; k < DTR; ++k) s = fmaf(r[k], Wd[k], s);
        float dt = (s > 20.f) ? s : log1pf(expf(s));
        float xv = xc[(size_t)(t0 + t) * DI + d];
        float dtx = dt * xv, acc = 0.f;
        #pragma unroll
        for (int n = 0; n < DS; ++n) {
            float dA = expf(dt * Av[n]);
            h[n] = fmaf(dA, h[n], dtx * r[DTR + n]);
            P[n] *= dA;
            acc = fmaf(h[n], r[DTR + DS + n], acc);
        }
        float yv = fmaf(xv, Dv, acc);
        if (c == 0) {   // chunk 0 is final: gate + bf16 split now
            float z = xz[(size_t)(t0 + t) * (2 * DI) + DI + d];
            float g = yv * siluf(z);
            unsigned short hi = f2bf(g);
            size_t base = (size_t)(t0 + t) * (2 * DI);
            Yp[base + d] = hi; Yp[base + DI + d] = hi;
        } else {
            y[(size_t)(t0 + t) * DI + d] = yv;
        }
    }
    size_t sb = ((size_t)(b * NCH + c) * DI + d) * DS;
    #pragma unroll
    for (int n = 0; n < DS; ++n) { Hend[sb + n] = h[n]; Pb[sb + n] = P[n]; }
}

// ---- scan pass 2: stitch carries into chunks 1..NCH-1, gate + split ----
__global__ __launch_bounds__(256)
void scan_p2(const float* __restrict__ dtbc, const float* __restrict__ xz,
             const float* __restrict__ dt_w, const float* __restrict__ dt_b,
             const float* __restrict__ A_log,
             const float* __restrict__ y, const float* __restrict__ Hend,
             const float* __restrict__ Pb, unsigned short* __restrict__ Yp) {
    int d = blockIdx.x * 256 + threadIdx.x;
    int b = blockIdx.y, c = blockIdx.z + 1;
    int t0 = b * LL + c * TCH;
    __shared__ float rs[TCH * 48];
    const float* src = dtbc + (size_t)t0 * 48;
    #pragma unroll
    for (int i = 0; i < 6; ++i) rs[threadIdx.x + i * 256] = src[threadIdx.x + i * 256];
    __syncthreads();
    float Av[DS], g[DS], Wd[DTR];
    #pragma unroll
    for (int n = 0; n < DS; ++n) Av[n] = -expf(A_log[d * DS + n]);
    #pragma unroll
    for (int k = 0; k < DTR; ++k) Wd[k] = dt_w[k * DI + d];
    float bias = dt_b[d];
    {   // g = true h at end of chunk c-1
        size_t sb0 = ((size_t)(b * NCH + 0) * DI + d) * DS;
        #pragma unroll
        for (int n = 0; n < DS; ++n) g[n] = Hend[sb0 + n];
        for (int cc = 1; cc < c; ++cc) {
            size_t sb = ((size_t)(b * NCH + cc) * DI + d) * DS;
            #pragma unroll
            for (int n = 0; n < DS; ++n) g[n] = fmaf(Pb[sb + n], g[n], Hend[sb + n]);
        }
    }
    for (int t = 0; t < TCH; ++t) {
        const float* r = rs + t * 48;
        float s = bias;
        #pragma unroll
        for (int k = 0; k < DTR; ++k) s = fmaf(r[k], Wd[k], s);
        float dt = (s > 20.f) ? s : log1pf(expf(s));
        float acc = 0.f;
        #pragma unroll
        for (int n = 0; n < DS; ++n) {
            g[n] *= expf(dt * Av[n]);
            acc = fmaf(g[n], r[DTR + DS + n], acc);
        }
        float yv = y[(size_t)(t0 + t) * DI + d] + acc;
        float z = xz[(size_t)(t0 + t) * (2 * DI) + DI + d];
        float gg = yv * siluf(z);
        unsigned short hi = f2bf(gg);
        size_t base = (size_t)(t0 + t) * (2 * DI);
        Yp[base + d] = hi; Yp[base + DI + d] = hi;
    }
}

extern "C" void kernel_launch(void* const* d_in, const int* in_sizes, int n_in,
                              void* d_out, int out_size, void* d_ws, size_t ws_size,
                              hipStream_t stream) {
    const int*   seq      = (const int*)d_in[0];
    const int*   attr     = (const int*)d_in[1];
    const float* item_emb = (const float*)d_in[2];
    const float* attr_emb = (const float*)d_in[3];
    const float* alpha    = (const float*)d_in[4];
    const float* ln_s     = (const float*)d_in[5];
    const float* ln_b     = (const float*)d_in[6];
    const float* in_w     = (const float*)d_in[7];
    const float* conv_w   = (const float*)d_in[8];
    const float* conv_b   = (const float*)d_in[9];
    const float* xp_w     = (const float*)d_in[10];
    const float* dt_w     = (const float*)d_in[11];
    const float* dt_b     = (const float*)d_in[12];
    const float* A_log    = (const float*)d_in[13];
    const float* D_p      = (const float*)d_in[14];
    const float* out_w    = (const float*)d_in[15];
    const float* nrm_s    = (const float*)d_in[16];
    const float* nrm_b    = (const float*)d_in[17];
    const float* head_w   = (const float*)d_in[18];
    float* out = (float*)d_out;

    // ---- workspace layout (byte offsets; peak 57.3 MB) ----
    char* w8 = (char*)d_ws;
    float*          x     = (float*)(w8);                      // [0, 4,194,304)
    unsigned short* Ap    = (unsigned short*)(w8 +  4194304);  // [4,194,304, 8,388,608)
    float*          Pb    = (float*)(w8 +  4194304);           //   overlays Ap (4,194,304 B exact)
    float*          xz    = (float*)(w8 +  8388608);           // [8,388,608, 25,165,824)
    float*          xc    = (float*)(w8 + 25165824);           // [25,165,824, 33,554,432)
    unsigned short* Xc3   = (unsigned short*)(w8 + 33554432);  // [33,554,432, 46,137,344)
    unsigned short* Yp    = (unsigned short*)(w8 + 33554432);  //   overlays Xc3[0:8.4MB]
    float*          Hend  = (float*)(w8 + 41943040);           //   overlays Xc3[8.4:12.6MB] (4,194,304 B exact)
    float*          yb    = (float*)(w8 + 46137344);           // [46,137,344, 54,525,952)
    float*          dtbc  = (float*)(w8 + 54525952);           // [54,525,952, 55,312,384)
    unsigned short* Btin  = (unsigned short*)(w8 + 55312384);  // 1,048,576
    unsigned short* Btxp  = (unsigned short*)(w8 + 56360960);  //   393,216
    unsigned short* Btout = (unsigned short*)(w8 + 56754176);  //   524,288 -> 57,278,464
    // head phase (everything except x dead):
    unsigned short* Ap3   = (unsigned short*)(w8 +  4194304);  // 6,291,456 -> ends 10,485,760
    unsigned short* Bth   = (unsigned short*)(w8 + 10485760);  // 46,202,880 -> ends 56,688,640

    embed_holo_ln<<<NTOK, 256, 0, stream>>>(seq, attr, item_emb, attr_emb, alpha, ln_s, ln_b, x);

    for (int l = 0; l < 4; ++l) {
        layer_prep<<<NTOK + 112, 256, 0, stream>>>(
            x, nrm_s + l * DM, nrm_b + l * DM, Ap,
            in_w + (size_t)l * DM * 1024, Btin,
            xp_w + (size_t)l * DI * 48, Btxp,
            out_w + (size_t)l * DI * DM, Btout);
        gemm_bf16t<false, false><<<dim3(8, 32), 256, 0, stream>>>(Ap, Btin, xz, 1024, 2 * DM);
        conv_silu<<<dim3(NTOK, 2), 256, 0, stream>>>(
            xz, conv_w + (size_t)l * DI * 4, conv_b + (size_t)l * DI, xc, Xc3);
        gemm_bf16t<false, false><<<dim3(1, 32), 256, 0, stream>>>(Xc3, Btxp, dtbc, 48, 3 * DI);
        scan_p1<<<dim3(2, BB, NCH), 256, 0, stream>>>(
            dtbc, xc, xz, dt_w + (size_t)l * DTR * DI, dt_b + (size_t)l * DI,
            A_log + (size_t)l * DI * DS, D_p + (size_t)l * DI, yb, Hend, Pb, Yp);
        scan_p2<<<dim3(2, BB, NCH - 1), 256, 0, stream>>>(
            dtbc, xz, dt_w + (size_t)l * DTR * DI, dt_b + (size_t)l * DI,
            A_log + (size_t)l * DI * DS, yb, Hend, Pb, Yp);
        gemm_bf16t<true, false><<<dim3(2, 32), 256, 0, stream>>>(Yp, Btout, x, DM, 2 * DI);
    }

    head_prep<<<512 + 1880, 256, 0, stream>>>(x, Ap3, head_w, Bth);
    gemm_bf16t<false, true><<<dim3(235, 32), 256, 0, stream>>>(Ap3, Bth, out, 30000, 3 * DM);
}